// Round 1
// baseline (2591.231 us; speedup 1.0000x reference)
//
#include <hip/hip_runtime.h>
#include <math.h>

#define LXY 256
#define NSITES (LXY * LXY)        // 65536
#define NSWEEPS 2
#define TOTAL (NSITES * NSWEEPS)  // 131072
#define BATCH 64
#define NBATCH (TOTAL / BATCH)    // 2048

// Single-wave exact-order Gibbs sampler.
// cell[site]: bits 0..2 = class value (0..4), bits 3..9 = batch mark (lane+1).
__global__ __launch_bounds__(64) void GibbsSampler_90443421319469_kernel(
    const int* __restrict__ Xi, const int* __restrict__ perm,
    const float* __restrict__ uni, const float* __restrict__ betap,
    int* __restrict__ out) {
#pragma clang fp contract(off)
  __shared__ __align__(16) unsigned short cell[NSITES];  // 128 KiB
  __shared__ float tab[96];  // tab[mx*9+n] = f32(exp(f64(fl(b*n)-fl(b*mx))))

  const int lane = threadIdx.x;  // 0..63
  const float beta = betap[0];

  // ---- stage lattice into LDS (int32 -> ushort) ----
  for (int g = lane; g < NSITES / 4; g += 64) {
    int4 x = ((const int4*)Xi)[g];
    ushort4 p;
    p.x = (unsigned short)x.x;
    p.y = (unsigned short)x.y;
    p.z = (unsigned short)x.z;
    p.w = (unsigned short)x.w;
    ((ushort4*)cell)[g] = p;
  }
  // ---- exp table (correctly rounded f32 via double exp) ----
  for (int e = lane; e < 81; e += 64) {
    int mxv = e / 9;
    int n = e - mxv * 9;
    float xn = beta * (float)n;   // fl(beta*n)  (no FMA: contract off)
    float xm = beta * (float)mxv; // fl(beta*mx)
    float d = xn - xm;
    tab[e] = (float)exp((double)d);
  }
  __syncthreads();

  // ---- prefetched batch inputs ----
  int uv = perm[lane];   // idx 0..63, sweep 0
  float r = uni[lane];

  for (int bi = 0; bi < NBATCH; ++bi) {
    // prefetch next batch (perm repeats per sweep; uniforms are flat [2*65536])
    int uv_n = 0;
    float r_n = 0.f;
    if (bi + 1 < NBATCH) {
      int nidx = (bi + 1) * BATCH + lane;
      uv_n = perm[nidx & (NSITES - 1)];
      r_n = uni[nidx];
    }

    const int u = uv >> 8, v = uv & 255;
    const int um = (u > 0) ? u - 1 : 0, up = (u < 255) ? u + 1 : 255;
    const int vm = (v > 0) ? v - 1 : 0, vp = (v < 255) ? v + 1 : 255;

    // ---- phase 1: set my mark (batch sites are distinct within a sweep) ----
    cell[uv] = (unsigned short)((cell[uv] & 7) | ((lane + 1) << 3));
    __syncthreads();

    // ---- phase 2: exact dep mask from my 3x3 neighborhood ----
    unsigned long long dep = 0ull;
    {
      int rr[3] = {um, u, up};
      int cc[3] = {vm, v, vp};
#pragma unroll
      for (int a = 0; a < 3; ++a) {
#pragma unroll
        for (int b = 0; b < 3; ++b) {
          int m = cell[(rr[a] << 8) | cc[b]] >> 3;
          if (m != 0 && (m - 1) < lane) dep |= (1ull << (m - 1));
        }
      }
    }
    __syncthreads();
    // clear my mark before execution rounds
    cell[uv] = (unsigned short)(cell[uv] & 7);
    __syncthreads();

    // ---- conflict-ordered execution rounds ----
    unsigned long long done = 0ull;
    bool mydone = false;
    for (int round = 0; round < BATCH; ++round) {
      bool ready = (!mydone) && ((dep & ~done) == 0ull);
      if (ready) {
        // gather 8 clipped neighbors; pack per-class counts in nibbles
        int acc = 0;
        acc += 1 << ((cell[(um << 8) | vm] & 7) << 2);
        acc += 1 << ((cell[(um << 8) | v ] & 7) << 2);
        acc += 1 << ((cell[(um << 8) | vp] & 7) << 2);
        acc += 1 << ((cell[(u  << 8) | vm] & 7) << 2);
        acc += 1 << ((cell[(u  << 8) | vp] & 7) << 2);
        acc += 1 << ((cell[(up << 8) | vm] & 7) << 2);
        acc += 1 << ((cell[(up << 8) | v ] & 7) << 2);
        acc += 1 << ((cell[(up << 8) | vp] & 7) << 2);
        int n0 = acc & 15, n1 = (acc >> 4) & 15;
        int n2 = (acc >> 8) & 15, n3 = (acc >> 12) & 15;
        int mxn = max(max(n0, n1), max(n2, n3));
        const float* trow = &tab[mxn * 9];
        float e0 = trow[n0], e1 = trow[n1], e2 = trow[n2], e3 = trow[n3];
        float s = ((e0 + e1) + e2) + e3;        // sequential, like np/XLA
        float c0 = e0 / s;                      // IEEE f32 divides, like ref
        int cnt = (c0 < r) ? 1 : 0;
        float c1 = c0 + e1 / s; cnt += (c1 < r) ? 1 : 0;
        float c2 = c1 + e2 / s; cnt += (c2 < r) ? 1 : 0;
        float c3 = c2 + e3 / s; cnt += (c3 < r) ? 1 : 0;
        cell[uv] = (unsigned short)cnt;         // value 0..4
      }
      __syncthreads();  // order this round's writes before next round's reads
      unsigned long long bal = __ballot(ready);
      done |= bal;
      mydone = mydone || ready;
      if (done == ~0ull) break;  // uniform exit
    }

    uv = uv_n;
    r = r_n;
  }

  __syncthreads();
  // ---- write back int32 lattice ----
  for (int g = lane; g < NSITES / 4; g += 64) {
    ushort4 p = ((ushort4*)cell)[g];
    int4 o;
    o.x = p.x & 7;
    o.y = p.y & 7;
    o.z = p.z & 7;
    o.w = p.w & 7;
    ((int4*)out)[g] = o;
  }
}

extern "C" void kernel_launch(void* const* d_in, const int* in_sizes, int n_in,
                              void* d_out, int out_size, void* d_ws,
                              size_t ws_size, hipStream_t stream) {
  const int* Xi = (const int*)d_in[0];      // X_init  (65536 int32)
  const int* perm = (const int*)d_in[1];    // perm    (65536 int32)
  const float* uni = (const float*)d_in[2]; // uniforms (131072 f32)
  const float* beta = (const float*)d_in[3];// beta scalar
  // d_in[4] = K (==4), hardcoded
  int* out = (int*)d_out;

  GibbsSampler_90443421319469_kernel<<<dim3(1), dim3(64), 0, stream>>>(
      Xi, perm, uni, beta, out);
}

// Round 2
// 391.579 us; speedup vs baseline: 6.6174x; 6.6174x over previous
//
#include <hip/hip_runtime.h>
#include <math.h>

#define NSITES 65536
#define TOTAL 131072
#define WIN 1024
#define NWIN 128   // total windows over 2 sweeps
#define NWIN1 64   // windows per sweep (schedule repeats across sweeps)

// ---------------------------------------------------------------------------
// Kernel 1: per-window round schedule (data-independent, parallel over 64 CUs)
// rounds[t]  = DAG level (1-based) of update t within its 1024-update window
// nrounds[w] = max level in window w
// ---------------------------------------------------------------------------
__global__ __launch_bounds__(64) void GibbsSched_kernel(
    const int* __restrict__ perm, unsigned char* __restrict__ rounds,
    int* __restrict__ nrounds) {
  __shared__ unsigned char rgrid[NSITES];  // 64 KiB: round of each site's update this window (0 = none)
  __shared__ unsigned char rnd64[64];      // assigned rounds, current sub-batch
  const int lane = threadIdx.x;
  const int w = blockIdx.x;  // 0..63

  for (int g = lane; g < NSITES / 16; g += 64)
    ((uint4*)rgrid)[g] = make_uint4(0u, 0u, 0u, 0u);
  __syncthreads();

  int wmax = 0;
  const int base_t = w * WIN;
  for (int sb = 0; sb < WIN / 64; ++sb) {
    const int t = base_t + sb * 64 + lane;
    const int uv = perm[t];
    const int u = uv >> 8, v = uv & 255;

    // exact intra-sub-batch dependency mask: i<lane with Chebyshev <= 1
    unsigned long long dep = 0ull;
    for (int i = 0; i < 64; ++i) {
      int uvi = __shfl(uv, i);
      int du = (uvi >> 8) - u; du = du < 0 ? -du : du;
      int dv = (uvi & 255) - v; dv = dv < 0 ? -dv : dv;
      if (i < lane && du <= 1 && dv <= 1) dep |= (1ull << i);
    }

    // base level from earlier sub-batches of this window (3x3 clipped max)
    const int um = u > 0 ? u - 1 : 0, up = u < 255 ? u + 1 : 255;
    const int vm = v > 0 ? v - 1 : 0, vp = v < 255 ? v + 1 : 255;
    int base = 0;
    {
      int rr[3] = {um, u, up}, cc[3] = {vm, v, vp};
#pragma unroll
      for (int a = 0; a < 3; ++a)
#pragma unroll
        for (int b = 0; b < 3; ++b)
          base = max(base, (int)rgrid[(rr[a] << 8) | cc[b]]);
    }

    rnd64[lane] = 0;
    __syncthreads();

    unsigned long long done = 0ull;
    bool asg = false;
    int myr = 0;
    for (;;) {
      bool ready = (!asg) && ((dep & ~done) == 0ull);
      if (ready) {
        int m = base;
        unsigned long long tt = dep;  // dep lanes are all assigned (earlier iters)
        while (tt) {
          int i = __ffsll(tt) - 1;
          m = max(m, (int)rnd64[i]);
          tt &= tt - 1;
        }
        myr = m + 1;
        rnd64[lane] = (unsigned char)myr;
      }
      done |= __ballot(ready);
      asg = asg || ready;
      __syncthreads();  // rnd64 visibility for next iteration
      if (done == ~0ull) break;
    }

    rgrid[uv] = (unsigned char)myr;  // sites distinct within window (one sweep)
    rounds[t] = (unsigned char)myr;
    wmax = max(wmax, myr);
    __syncthreads();  // rgrid writes visible before next sub-batch's base reads
  }

  for (int off = 32; off; off >>= 1) wmax = max(wmax, __shfl_down(wmax, off));
  if (lane == 0) nrounds[w] = wmax;
}

// ---------------------------------------------------------------------------
// Kernel 2: sequential executor — 1 block x 1024 threads, 16 waves.
// Per window: rd = 1..nr, thread fires in its precomputed round. Same-round
// updates are mutually Chebyshev>=2 => disjoint read/write sets.
// ---------------------------------------------------------------------------
__global__ __launch_bounds__(1024) void GibbsSampler_90443421319469_kernel(
    const int* __restrict__ Xi, const int* __restrict__ perm,
    const float* __restrict__ uni, const float* __restrict__ betap,
    const unsigned char* __restrict__ rounds, const int* __restrict__ nrounds,
    int* __restrict__ out) {
#pragma clang fp contract(off)
  __shared__ unsigned char cell[NSITES];  // 64 KiB lattice, values 0..4
  __shared__ float tab[96];  // tab[mx*9+n] = f32(exp(f64(fl(b*n)-fl(b*mx))))
  const int tid = threadIdx.x;
  const float beta = betap[0];

  for (int g = tid; g < NSITES / 4; g += 1024) {
    int4 x = ((const int4*)Xi)[g];
    uchar4 p;
    p.x = (unsigned char)x.x; p.y = (unsigned char)x.y;
    p.z = (unsigned char)x.z; p.w = (unsigned char)x.w;
    ((uchar4*)cell)[g] = p;
  }
  if (tid < 81) {
    int mxv = tid / 9, n = tid - mxv * 9;
    float xn = beta * (float)n;   // fl(beta*n), no FMA (contract off)
    float xm = beta * (float)mxv; // fl(beta*mx)
    tab[tid] = (float)exp((double)(xn - xm));
  }
  __syncthreads();

  // prefetched per-window inputs
  int uv = perm[tid];
  float r = uni[tid];
  int rme = rounds[tid];
  int nr = nrounds[0];

  for (int w = 0; w < NWIN; ++w) {
    int uv_n = 0, rme_n = 0, nr_n = 0;
    float r_n = 0.f;
    if (w + 1 < NWIN) {
      int idx = (w + 1) * WIN + tid;
      uv_n = perm[idx & (NSITES - 1)];
      r_n = uni[idx];
      rme_n = rounds[idx & (NSITES - 1)];
      nr_n = nrounds[(w + 1) & (NWIN1 - 1)];
    }

    const int u = uv >> 8, v = uv & 255;
    const int um = u > 0 ? u - 1 : 0, up = u < 255 ? u + 1 : 255;
    const int vm = v > 0 ? v - 1 : 0, vp = v < 255 ? v + 1 : 255;

    for (int rd = 1; rd <= nr; ++rd) {  // nr is block-uniform
      if (rme == rd) {
        int acc = 0;  // per-class counts packed in nibbles (class 4 -> bit 16, ignored)
        acc += 1 << (cell[(um << 8) | vm] << 2);
        acc += 1 << (cell[(um << 8) | v ] << 2);
        acc += 1 << (cell[(um << 8) | vp] << 2);
        acc += 1 << (cell[(u  << 8) | vm] << 2);
        acc += 1 << (cell[(u  << 8) | vp] << 2);
        acc += 1 << (cell[(up << 8) | vm] << 2);
        acc += 1 << (cell[(up << 8) | v ] << 2);
        acc += 1 << (cell[(up << 8) | vp] << 2);
        int n0 = acc & 15, n1 = (acc >> 4) & 15;
        int n2 = (acc >> 8) & 15, n3 = (acc >> 12) & 15;
        int mxn = max(max(n0, n1), max(n2, n3));
        const float* trow = &tab[mxn * 9];
        float e0 = trow[n0], e1 = trow[n1], e2 = trow[n2], e3 = trow[n3];
        float s = ((e0 + e1) + e2) + e3;  // sequential sum, like np/XLA
        float c0 = e0 / s;                // IEEE f32 divides, like ref
        int cnt = (c0 < r) ? 1 : 0;
        float c1 = c0 + e1 / s; cnt += (c1 < r) ? 1 : 0;
        float c2 = c1 + e2 / s; cnt += (c2 < r) ? 1 : 0;
        float c3 = c2 + e3 / s; cnt += (c3 < r) ? 1 : 0;
        cell[uv] = (unsigned char)cnt;  // 0..4
      }
      __syncthreads();  // order round rd writes before round rd+1 reads
    }

    uv = uv_n; r = r_n; rme = rme_n; nr = nr_n;
  }

  // last inner iteration ended with __syncthreads(): cell is coherent
  for (int g = tid; g < NSITES / 4; g += 1024) {
    uchar4 p = ((uchar4*)cell)[g];
    int4 o;
    o.x = p.x; o.y = p.y; o.z = p.z; o.w = p.w;
    ((int4*)out)[g] = o;
  }
}

extern "C" void kernel_launch(void* const* d_in, const int* in_sizes, int n_in,
                              void* d_out, int out_size, void* d_ws,
                              size_t ws_size, hipStream_t stream) {
  const int* Xi = (const int*)d_in[0];       // X_init  (65536 int32)
  const int* perm = (const int*)d_in[1];     // perm    (65536 int32)
  const float* uni = (const float*)d_in[2];  // uniforms (131072 f32)
  const float* beta = (const float*)d_in[3]; // beta scalar
  // d_in[4] = K (==4), hardcoded
  int* out = (int*)d_out;

  unsigned char* rounds = (unsigned char*)d_ws;           // 65536 B
  int* nrounds = (int*)((char*)d_ws + NSITES);            // 256 B

  GibbsSched_kernel<<<dim3(NWIN1), dim3(64), 0, stream>>>(perm, rounds,
                                                          nrounds);
  GibbsSampler_90443421319469_kernel<<<dim3(1), dim3(1024), 0, stream>>>(
      Xi, perm, uni, beta, rounds, nrounds, out);
}

// Round 3
// 345.642 us; speedup vs baseline: 7.4969x; 1.1329x over previous
//
#include <hip/hip_runtime.h>
#include <math.h>

#define NSITES 65536
#define WIN 4096
#define NW 16          // windows per sweep
#define SB (WIN / 64)  // 64 sub-batches of 64 per window
#define RMAX 64        // tracked rounds per window (depth ~6 in practice)

// ws layout: sorted ushort[NSITES] (128 KiB) | ends int[NW*RMAX] (4 KiB)

// ---------------------------------------------------------------------------
// Kernel 1: per-window DAG leveling + counting sort by round.
// grid[site]: low 8 bits = round (0=none), high 8 bits = sub-batch mark lane+1.
// ---------------------------------------------------------------------------
__global__ __launch_bounds__(64) void GibbsSched_kernel(
    const int* __restrict__ perm, unsigned short* __restrict__ sorted,
    int* __restrict__ ends) {
  __shared__ unsigned short grid[NSITES];  // 128 KiB
  __shared__ unsigned char wloc[WIN];      // round per local update
  __shared__ unsigned char rnd64[64];
  __shared__ int cnt[256];
  __shared__ int coff[256];
  const int lane = threadIdx.x;
  const int w = blockIdx.x;
  const int pbase = w * WIN;

  for (int g = lane; g < NSITES * 2 / 16; g += 64)
    ((uint4*)grid)[g] = make_uint4(0u, 0u, 0u, 0u);
  for (int g = lane; g < 256; g += 64) cnt[g] = 0;
  __syncthreads();

  int uv = perm[pbase + lane];
  for (int sb = 0; sb < SB; ++sb) {
    int uv_n = (sb + 1 < SB) ? perm[pbase + (sb + 1) * 64 + lane] : 0;
    const int u = uv >> 8, v = uv & 255;
    grid[uv] = (unsigned short)((lane + 1) << 8);  // sites unique per window
    __syncthreads();

    const int um = u ? u - 1 : 0, up = u < 255 ? u + 1 : 255;
    const int vm = v ? v - 1 : 0, vp = v < 255 ? v + 1 : 255;
    unsigned long long dep = 0ull;
    int base = 0;
    {
      int rr[3] = {um, u, up}, cc[3] = {vm, v, vp};
#pragma unroll
      for (int a = 0; a < 3; ++a)
#pragma unroll
        for (int b = 0; b < 3; ++b) {
          int e = grid[(rr[a] << 8) | cc[b]];
          base = max(base, e & 255);      // rounds of earlier sub-batches
          int m = e >> 8;                 // marks of this sub-batch
          if (m && (m - 1) < lane) dep |= 1ull << (m - 1);
        }
    }

    unsigned long long done = 0ull;
    bool asg = false;
    int myr = 0;
    for (;;) {
      bool ready = !asg && ((dep & ~done) == 0ull);
      if (ready) {
        int m = base;
        unsigned long long tt = dep;  // dep lanes assigned in earlier iters
        while (tt) {
          int i = __ffsll(tt) - 1;
          m = max(m, (int)rnd64[i]);
          tt &= tt - 1;
        }
        myr = m + 1;
        rnd64[lane] = (unsigned char)myr;
      }
      done |= __ballot(ready);
      asg = asg || ready;
      __syncthreads();
      if (done == ~0ull) break;
    }

    grid[uv] = (unsigned short)myr;  // commit round, clear my mark
    wloc[sb * 64 + lane] = (unsigned char)myr;
    atomicAdd(&cnt[myr & 255], 1);
    __syncthreads();
    uv = uv_n;
  }

  if (lane == 0) {
    int e = 0;
    for (int r = 0; r < 256; ++r) {
      coff[r] = e;  // start of round r
      e += cnt[r];
      if (r < RMAX) ends[w * RMAX + r] = e;  // cumulative end through round r
    }
  }
  __syncthreads();

  for (int sb = 0; sb < SB; ++sb) {
    int idx = sb * 64 + lane;
    int r = wloc[idx];
    int pos = atomicAdd(&coff[r], 1);
    sorted[pbase + pos] = (unsigned short)idx;  // order within round arbitrary
  }
}

// ---------------------------------------------------------------------------
// Kernel 2: executor — 1 block x 1024 threads; dense round slices.
// ---------------------------------------------------------------------------
__global__ __launch_bounds__(1024) void GibbsSampler_90443421319469_kernel(
    const int* __restrict__ Xi, const int* __restrict__ perm,
    const float* __restrict__ uni, const float* __restrict__ betap,
    const unsigned short* __restrict__ sorted, const int* __restrict__ ends,
    int* __restrict__ out) {
#pragma clang fp contract(off)
  __shared__ unsigned char cell[NSITES];  // 64 KiB lattice, values 0..4
  __shared__ float tab[96];
  __shared__ int lend[NW * RMAX];  // 4 KiB, all windows' round boundaries
  const int tid = threadIdx.x;
  const float beta = betap[0];

  for (int g = tid; g < NSITES / 4; g += 1024) {
    int4 x = ((const int4*)Xi)[g];
    uchar4 p;
    p.x = (unsigned char)x.x; p.y = (unsigned char)x.y;
    p.z = (unsigned char)x.z; p.w = (unsigned char)x.w;
    ((uchar4*)cell)[g] = p;
  }
  lend[tid] = ends[tid];  // NW*RMAX == 1024 exactly
  if (tid < 81) {
    int mxv = tid / 9, n = tid - mxv * 9;
    float xn = beta * (float)n;   // fl(beta*n), no FMA (contract off)
    float xm = beta * (float)mxv; // fl(beta*mx)
    tab[tid] = (float)exp((double)(xn - xm));
  }
  __syncthreads();

  for (int w = 0; w < 2 * NW; ++w) {
    const int ww = w & (NW - 1);        // window within sweep
    const int sw = w >> 4;              // sweep index (NW==16)
    const int pbase = ww * WIN;         // into perm/sorted
    const int ubase = sw * NSITES + pbase;  // into uniforms
    const int* le = &lend[ww * RMAX];

    for (int rd = 1; rd < RMAX; ++rd) {
      const int b = le[rd - 1], e = le[rd];
      if (b >= WIN) break;  // uniform: all updates of window done
      for (int i = b + tid; i < e; i += 1024) {
        const int s = sorted[pbase + i];
        const int uvv = perm[pbase + s];
        const float r = uni[ubase + s];
        const int u = uvv >> 8, v = uvv & 255;
        const int um = u ? u - 1 : 0, up = u < 255 ? u + 1 : 255;
        const int vm = v ? v - 1 : 0, vp = v < 255 ? v + 1 : 255;
        int acc = 0;  // per-class counts in nibbles (class 4 -> bit16, unused)
        acc += 1 << (cell[(um << 8) | vm] << 2);
        acc += 1 << (cell[(um << 8) | v ] << 2);
        acc += 1 << (cell[(um << 8) | vp] << 2);
        acc += 1 << (cell[(u  << 8) | vm] << 2);
        acc += 1 << (cell[(u  << 8) | vp] << 2);
        acc += 1 << (cell[(up << 8) | vm] << 2);
        acc += 1 << (cell[(up << 8) | v ] << 2);
        acc += 1 << (cell[(up << 8) | vp] << 2);
        const int n0 = acc & 15, n1 = (acc >> 4) & 15;
        const int n2 = (acc >> 8) & 15, n3 = (acc >> 12) & 15;
        const int mxn = max(max(n0, n1), max(n2, n3));
        const float* trow = &tab[mxn * 9];
        const float e0 = trow[n0], e1 = trow[n1], e2 = trow[n2], e3 = trow[n3];
        const float s4 = ((e0 + e1) + e2) + e3;  // sequential sum, like np/XLA
        const float c0 = e0 / s4;                // IEEE f32 divides, like ref
        int cnt = (c0 < r) ? 1 : 0;
        const float c1 = c0 + e1 / s4; cnt += (c1 < r) ? 1 : 0;
        const float c2 = c1 + e2 / s4; cnt += (c2 < r) ? 1 : 0;
        const float c3 = c2 + e3 / s4; cnt += (c3 < r) ? 1 : 0;
        cell[uvv] = (unsigned char)cnt;  // 0..4
      }
      __syncthreads();  // round rd writes before round rd+1 reads
    }
  }

  for (int g = tid; g < NSITES / 4; g += 1024) {
    uchar4 p = ((uchar4*)cell)[g];
    int4 o;
    o.x = p.x; o.y = p.y; o.z = p.z; o.w = p.w;
    ((int4*)out)[g] = o;
  }
}

extern "C" void kernel_launch(void* const* d_in, const int* in_sizes, int n_in,
                              void* d_out, int out_size, void* d_ws,
                              size_t ws_size, hipStream_t stream) {
  const int* Xi = (const int*)d_in[0];
  const int* perm = (const int*)d_in[1];
  const float* uni = (const float*)d_in[2];
  const float* beta = (const float*)d_in[3];
  int* out = (int*)d_out;

  unsigned short* sorted = (unsigned short*)d_ws;                 // 128 KiB
  int* ends = (int*)((char*)d_ws + NSITES * sizeof(unsigned short));  // 4 KiB

  GibbsSched_kernel<<<dim3(NW), dim3(64), 0, stream>>>(perm, sorted, ends);
  GibbsSampler_90443421319469_kernel<<<dim3(1), dim3(1024), 0, stream>>>(
      Xi, perm, uni, beta, sorted, ends, out);
}

// Round 4
// 276.857 us; speedup vs baseline: 9.3594x; 1.2484x over previous
//
#include <hip/hip_runtime.h>
#include <math.h>

#define NSITES 65536
#define WIN 4096
#define NW 16          // windows per sweep
#define RMAX 64        // tracked rounds per window (observed depth ~6)

// ws layout:
//   inv    ushort[NSITES]     131072 B
//   recuv  ushort[NSITES]     131072 B
//   recr   float [2*NSITES]   524288 B
//   ends   int   [NW*RMAX]      4096 B

// ---------------------------------------------------------------------------
// Kernel A: inverse permutation (position of each site within the sweep)
// ---------------------------------------------------------------------------
__global__ __launch_bounds__(1024) void GibbsInv_kernel(
    const int* __restrict__ perm, unsigned short* __restrict__ inv) {
  const int t = blockIdx.x * 1024 + threadIdx.x;
  inv[perm[t]] = (unsigned short)t;
}

// wave-aggregated atomic rank: returns this lane's position for value v in
// counter array c (1-based values, v <= vmax; vmax wave-uniform).
__device__ __forceinline__ int agg_pos(int v, int* c, int vmax) {
  int pos = 0;
  const int lane = threadIdx.x & 63;
  for (int vv = 1; vv <= vmax; ++vv) {
    unsigned long long m = __ballot(v == vv);
    if (m) {
      int leader = __ffsll((long long)m) - 1;
      int base = 0;
      if (lane == leader) base = atomicAdd(&c[vv], (int)__popcll(m));
      base = __shfl(base, leader);
      if (v == vv) pos = base + (int)__popcll(m & ((1ull << lane) - 1ull));
    }
  }
  return pos;
}

// ---------------------------------------------------------------------------
// Kernel B: per-window DAG leveling (Jacobi fixpoint) + counting sort +
// record gather. One 1024-thread block per window; each thread owns 4 nodes.
// ---------------------------------------------------------------------------
__global__ __launch_bounds__(1024) void GibbsSched_kernel(
    const int* __restrict__ perm, const unsigned short* __restrict__ inv,
    const float* __restrict__ uni, unsigned short* __restrict__ recuv,
    float* __restrict__ recr, int* __restrict__ ends) {
  __shared__ unsigned short lvl[WIN];  // 8 KiB
  __shared__ int cnt[RMAX + 1], coff[RMAX + 1];
  __shared__ int chg, bmax;
  const int tid = threadIdx.x;
  const int w = blockIdx.x;
  const int wbase = w * WIN;

  for (int i = tid; i < RMAX + 1; i += 1024) { cnt[i] = 0; coff[i] = 0; }
  if (tid == 0) bmax = 0;

  int uvk[4];
  unsigned short pred[4][8];
  int myl[4];
#pragma unroll
  for (int k = 0; k < 4; ++k) {
    const int lt = tid + k * 1024;
    const int uv = perm[wbase + lt];
    uvk[k] = uv;
    const int u = uv >> 8, v = uv & 255;
    const int um = u ? u - 1 : 0, up = u < 255 ? u + 1 : 255;
    const int vm = v ? v - 1 : 0, vp = v < 255 ? v + 1 : 255;
    const int nb8[8] = {(um << 8) | vm, (um << 8) | v, (um << 8) | vp,
                        (u << 8) | vm,                 (u << 8) | vp,
                        (up << 8) | vm, (up << 8) | v, (up << 8) | vp};
#pragma unroll
    for (int j = 0; j < 8; ++j) {
      const int p = inv[nb8[j]];  // position of that site in the sweep
      // in-window, strictly-earlier => true dependency (clipped dup == self
      // gives p == wbase+lt, excluded by <)
      pred[k][j] = (p >= wbase && p < wbase + lt)
                       ? (unsigned short)(p - wbase) : (unsigned short)0xFFFF;
    }
    lvl[lt] = 1;
    myl[k] = 1;
  }
  __syncthreads();

  // monotone Jacobi relaxation: lvl[t] = 1 + max(lvl[preds]); unique fixpoint
  for (int pass = 0; pass < RMAX; ++pass) {
    if (tid == 0) chg = 0;
    __syncthreads();
    bool ch = false;
#pragma unroll
    for (int k = 0; k < 4; ++k) {
      int m = 0;
#pragma unroll
      for (int j = 0; j < 8; ++j) {
        const unsigned short p = pred[k][j];
        if (p != 0xFFFF) m = max(m, (int)lvl[p]);
      }
      const int nl = m + 1;  // >= myl[k] (levels only grow)
      if (nl != myl[k]) {
        myl[k] = nl;
        lvl[tid + k * 1024] = (unsigned short)nl;
        ch = true;
      }
    }
    if (ch) chg = 1;
    __syncthreads();
    if (chg == 0) break;  // a no-change pass == consistent fixpoint
  }

#pragma unroll
  for (int k = 0; k < 4; ++k) atomicMax(&bmax, myl[k]);
  __syncthreads();
  const int vmax = bmax;

#pragma unroll
  for (int k = 0; k < 4; ++k) (void)agg_pos(myl[k], cnt, vmax);  // histogram
  __syncthreads();
  if (tid == 0) {
    int e = 0;
    for (int r = 0; r < RMAX; ++r) {  // cnt[0]==0
      coff[r] = e;
      e += cnt[r];
      ends[w * RMAX + r] = e;  // cumulative end through round r
    }
  }
  __syncthreads();

#pragma unroll
  for (int k = 0; k < 4; ++k) {
    const int pos = agg_pos(myl[k], coff, vmax);
    const int lt = tid + k * 1024;
    recuv[wbase + pos] = (unsigned short)uvk[k];
    recr[wbase + pos] = uni[wbase + lt];                    // sweep 0
    recr[NSITES + wbase + pos] = uni[NSITES + wbase + lt];  // sweep 1
  }
}

// ---------------------------------------------------------------------------
// Kernel C: executor — 1 block x 1024 threads; dense round slices with
// coalesced prefetched records.
// ---------------------------------------------------------------------------
__device__ __forceinline__ void do_update(unsigned char* cell,
                                          const float* tab, int uvv, float r) {
  const int u = uvv >> 8, v = uvv & 255;
  const int um = u ? u - 1 : 0, up = u < 255 ? u + 1 : 255;
  const int vm = v ? v - 1 : 0, vp = v < 255 ? v + 1 : 255;
  int acc = 0;  // per-class counts in nibbles (class 4 -> bit16, unused)
  acc += 1 << (cell[(um << 8) | vm] << 2);
  acc += 1 << (cell[(um << 8) | v ] << 2);
  acc += 1 << (cell[(um << 8) | vp] << 2);
  acc += 1 << (cell[(u  << 8) | vm] << 2);
  acc += 1 << (cell[(u  << 8) | vp] << 2);
  acc += 1 << (cell[(up << 8) | vm] << 2);
  acc += 1 << (cell[(up << 8) | v ] << 2);
  acc += 1 << (cell[(up << 8) | vp] << 2);
  const int n0 = acc & 15, n1 = (acc >> 4) & 15;
  const int n2 = (acc >> 8) & 15, n3 = (acc >> 12) & 15;
  const int mxn = max(max(n0, n1), max(n2, n3));
  const float* trow = &tab[mxn * 9];
  const float e0 = trow[n0], e1 = trow[n1], e2 = trow[n2], e3 = trow[n3];
  const float s4 = ((e0 + e1) + e2) + e3;  // sequential sum, like np/XLA
  const float c0 = e0 / s4;                // IEEE f32 divides, like ref
  int cnt = (c0 < r) ? 1 : 0;
  const float c1 = c0 + e1 / s4; cnt += (c1 < r) ? 1 : 0;
  const float c2 = c1 + e2 / s4; cnt += (c2 < r) ? 1 : 0;
  const float c3 = c2 + e3 / s4; cnt += (c3 < r) ? 1 : 0;
  cell[uvv] = (unsigned char)cnt;  // 0..4
}

__global__ __launch_bounds__(1024) void GibbsSampler_90443421319469_kernel(
    const int* __restrict__ Xi, const unsigned short* __restrict__ recuv,
    const float* __restrict__ recr, const float* __restrict__ betap,
    const int* __restrict__ ends, int* __restrict__ out) {
#pragma clang fp contract(off)
  __shared__ unsigned char cell[NSITES];  // 64 KiB
  __shared__ float tab[96];
  __shared__ int lend[NW * RMAX];  // 4 KiB
  const int tid = threadIdx.x;
  const float beta = betap[0];

  for (int g = tid; g < NSITES / 4; g += 1024) {
    int4 x = ((const int4*)Xi)[g];
    uchar4 p;
    p.x = (unsigned char)x.x; p.y = (unsigned char)x.y;
    p.z = (unsigned char)x.z; p.w = (unsigned char)x.w;
    ((uchar4*)cell)[g] = p;
  }
  lend[tid] = ends[tid];  // NW*RMAX == 1024
  if (tid < 81) {
    const int mxv = tid / 9, n = tid - mxv * 9;
    const float xn = beta * (float)n;   // fl(beta*n), no FMA (contract off)
    const float xm = beta * (float)mxv; // fl(beta*mx)
    tab[tid] = (float)exp((double)(xn - xm));
  }
  __syncthreads();

  for (int w = 0; w < 2 * NW; ++w) {
    const int ww = w & (NW - 1);
    const int sw = w >> 4;  // sweep index (NW==16)
    const int pbase = ww * WIN;
    const unsigned short* ru = recuv + pbase;
    const float* rr = recr + sw * NSITES + pbase;
    const int* le = &lend[ww * RMAX];

    int nb = 0, ne = le[1];
    int cu = 0; float cr = 0.f;
    if (tid < ne) { cu = ru[tid]; cr = rr[tid]; }  // round-1 first iter

    for (int rd = 1; rd < RMAX; ++rd) {
      const int b = nb, e = ne;
      if (b >= WIN) break;  // uniform: window complete
      nb = e;
      ne = (rd + 1 < RMAX) ? le[rd + 1] : e;
      // prefetch next round's first-iter record (independent of cell state)
      int pu = 0; float pr = 0.f;
      if (nb + tid < ne) { pu = ru[nb + tid]; pr = rr[nb + tid]; }
      // execute current round
      if (b + tid < e) do_update(cell, tab, cu, cr);
      for (int i = b + tid + 1024; i < e; i += 1024)
        do_update(cell, tab, ru[i], rr[i]);
      __syncthreads();  // round rd writes before round rd+1 reads
      cu = pu; cr = pr;
    }
  }

  for (int g = tid; g < NSITES / 4; g += 1024) {
    uchar4 p = ((uchar4*)cell)[g];
    int4 o;
    o.x = p.x; o.y = p.y; o.z = p.z; o.w = p.w;
    ((int4*)out)[g] = o;
  }
}

extern "C" void kernel_launch(void* const* d_in, const int* in_sizes, int n_in,
                              void* d_out, int out_size, void* d_ws,
                              size_t ws_size, hipStream_t stream) {
  const int* Xi = (const int*)d_in[0];
  const int* perm = (const int*)d_in[1];
  const float* uni = (const float*)d_in[2];
  const float* beta = (const float*)d_in[3];
  int* out = (int*)d_out;

  char* ws = (char*)d_ws;
  unsigned short* inv = (unsigned short*)ws;                    // 128 KiB
  unsigned short* recuv = (unsigned short*)(ws + 131072);       // 128 KiB
  float* recr = (float*)(ws + 262144);                          // 512 KiB
  int* ends = (int*)(ws + 786432);                              // 4 KiB

  GibbsInv_kernel<<<dim3(64), dim3(1024), 0, stream>>>(perm, inv);
  GibbsSched_kernel<<<dim3(NW), dim3(1024), 0, stream>>>(perm, inv, uni,
                                                         recuv, recr, ends);
  GibbsSampler_90443421319469_kernel<<<dim3(1), dim3(1024), 0, stream>>>(
      Xi, recuv, recr, beta, ends, out);
}

// Round 5
// 268.120 us; speedup vs baseline: 9.6645x; 1.0326x over previous
//
#include <hip/hip_runtime.h>
#include <math.h>

#define NSITES 65536
#define WIN 4096
#define NW 16          // windows per sweep
#define RMAX 64        // tracked rounds per window (observed depth ~7)

// ws layout:
//   recuv  ushort[NSITES]     131072 B   (site per sorted slot; sweep-invariant)
//   recr   float [2*NSITES]   524288 B   (uniform per sorted slot, per sweep)
//   ends   int   [NW*RMAX]      4096 B   (cumulative round boundaries)

// wave-aggregated atomic rank: position for value v in counter array c
// (1-based values, v <= vmax; vmax wave-uniform).
__device__ __forceinline__ int agg_pos(int v, int* c, int vmax) {
  int pos = 0;
  const int lane = threadIdx.x & 63;
  for (int vv = 1; vv <= vmax; ++vv) {
    unsigned long long m = __ballot(v == vv);
    if (m) {
      int leader = __ffsll((long long)m) - 1;
      int base = 0;
      if (lane == leader) base = atomicAdd(&c[vv], (int)__popcll(m));
      base = __shfl(base, leader);
      if (v == vv) pos = base + (int)__popcll(m & ((1ull << lane) - 1ull));
    }
  }
  return pos;
}

// ---------------------------------------------------------------------------
// Kernel A: per-window DAG leveling + counting sort + record gather.
// One 1024-thread block per window; window-local position grid in LDS
// (no global inverse-permutation pass needed).
// ---------------------------------------------------------------------------
__global__ __launch_bounds__(1024) void GibbsSched_kernel(
    const int* __restrict__ perm, const float* __restrict__ uni,
    unsigned short* __restrict__ recuv, float* __restrict__ recr,
    int* __restrict__ ends) {
  __shared__ unsigned short posg[NSITES];  // 128 KiB: local pos+1, 0 = absent
  __shared__ unsigned short lvl[WIN];      // 8 KiB
  __shared__ int cnt[RMAX + 1], coff[RMAX + 1];
  __shared__ int chg, bmax;
  const int tid = threadIdx.x;
  const int w = blockIdx.x;
  const int wbase = w * WIN;

  for (int g = tid; g < NSITES / 8; g += 1024)  // 8 ushorts per uint4
    ((uint4*)posg)[g] = make_uint4(0u, 0u, 0u, 0u);
  for (int i = tid; i <= RMAX; i += 1024) { cnt[i] = 0; coff[i] = 0; }
  if (tid == 0) bmax = 0;
  __syncthreads();

  int uvk[4];
#pragma unroll
  for (int k = 0; k < 4; ++k) {
    const int lt = tid + k * 1024;
    uvk[k] = perm[wbase + lt];
    posg[uvk[k]] = (unsigned short)(lt + 1);  // sites unique within a sweep
  }
  __syncthreads();

  unsigned short pred[4][8];
  int myl[4];
#pragma unroll
  for (int k = 0; k < 4; ++k) {
    const int lt = tid + k * 1024;
    const int uv = uvk[k], u = uv >> 8, v = uv & 255;
    const int um = u ? u - 1 : 0, up = u < 255 ? u + 1 : 255;
    const int vm = v ? v - 1 : 0, vp = v < 255 ? v + 1 : 255;
    const int nb8[8] = {(um << 8) | vm, (um << 8) | v, (um << 8) | vp,
                        (u << 8) | vm,                 (u << 8) | vp,
                        (up << 8) | vm, (up << 8) | v, (up << 8) | vp};
#pragma unroll
    for (int j = 0; j < 8; ++j) {
      const int p = posg[nb8[j]];  // clipped dup == self -> p-1==lt, excluded
      pred[k][j] = (p && p - 1 < lt) ? (unsigned short)(p - 1)
                                     : (unsigned short)0xFFFF;
    }
    lvl[lt] = 1;
    myl[k] = 1;
  }
  __syncthreads();

  // monotone Jacobi relaxation to the unique longest-path fixpoint
  for (int pass = 0; pass < 128; ++pass) {
    if (tid == 0) chg = 0;
    __syncthreads();
    bool ch = false;
#pragma unroll
    for (int k = 0; k < 4; ++k) {
      int m = 0;
#pragma unroll
      for (int j = 0; j < 8; ++j) {
        const unsigned short p = pred[k][j];
        if (p != 0xFFFF) m = max(m, (int)lvl[p]);
      }
      const int nl = m + 1;  // levels only grow
      if (nl != myl[k]) {
        myl[k] = nl;
        lvl[tid + k * 1024] = (unsigned short)nl;
        ch = true;
      }
    }
    if (ch) chg = 1;
    __syncthreads();
    if (chg == 0) break;  // full no-change pass == converged
  }

#pragma unroll
  for (int k = 0; k < 4; ++k) atomicMax(&bmax, myl[k]);
  __syncthreads();
  const int vmax = bmax;

#pragma unroll
  for (int k = 0; k < 4; ++k) (void)agg_pos(myl[k], cnt, vmax);  // histogram
  __syncthreads();
  if (tid == 0) {
    int e = 0;
    for (int r = 0; r < RMAX; ++r) {  // cnt[0]==0
      coff[r] = e;
      e += cnt[r];
      ends[w * RMAX + r] = e;  // cumulative end through round r
    }
  }
  __syncthreads();

#pragma unroll
  for (int k = 0; k < 4; ++k) {
    const int pos = agg_pos(myl[k], coff, vmax);
    const int lt = tid + k * 1024;
    recuv[wbase + pos] = (unsigned short)uvk[k];
    recr[wbase + pos] = uni[wbase + lt];                    // sweep 0
    recr[NSITES + wbase + pos] = uni[NSITES + wbase + lt];  // sweep 1
  }
}

// ---------------------------------------------------------------------------
// Kernel B: executor — 1 block x 1024 threads. Round slices read records
// from a double-buffered LDS window; next window staged during round 1.
// ---------------------------------------------------------------------------
__device__ __forceinline__ void do_update(unsigned char* cell,
                                          const float* tab, int uvv, float r) {
#pragma clang fp contract(off)
  const int u = uvv >> 8, v = uvv & 255;
  const int um = u ? u - 1 : 0, up = u < 255 ? u + 1 : 255;
  const int vm = v ? v - 1 : 0, vp = v < 255 ? v + 1 : 255;
  int acc = 0;  // per-class counts in nibbles (class 4 -> bit16, unused)
  acc += 1 << (cell[(um << 8) | vm] << 2);
  acc += 1 << (cell[(um << 8) | v ] << 2);
  acc += 1 << (cell[(um << 8) | vp] << 2);
  acc += 1 << (cell[(u  << 8) | vm] << 2);
  acc += 1 << (cell[(u  << 8) | vp] << 2);
  acc += 1 << (cell[(up << 8) | vm] << 2);
  acc += 1 << (cell[(up << 8) | v ] << 2);
  acc += 1 << (cell[(up << 8) | vp] << 2);
  const int n0 = acc & 15, n1 = (acc >> 4) & 15;
  const int n2 = (acc >> 8) & 15, n3 = (acc >> 12) & 15;
  const int mxn = max(max(n0, n1), max(n2, n3));
  const float* trow = &tab[mxn * 9];
  const float e0 = trow[n0], e1 = trow[n1], e2 = trow[n2], e3 = trow[n3];
  const float s4 = ((e0 + e1) + e2) + e3;  // sequential sum, like np/XLA
  const float c0 = e0 / s4;                // IEEE f32 divides, like ref
  int cnt = (c0 < r) ? 1 : 0;
  const float c1 = c0 + e1 / s4; cnt += (c1 < r) ? 1 : 0;
  const float c2 = c1 + e2 / s4; cnt += (c2 < r) ? 1 : 0;
  const float c3 = c2 + e3 / s4; cnt += (c3 < r) ? 1 : 0;
  cell[uvv] = (unsigned char)cnt;  // 0..4
}

__global__ __launch_bounds__(1024) void GibbsSampler_90443421319469_kernel(
    const int* __restrict__ Xi, const unsigned short* __restrict__ recuv,
    const float* __restrict__ recr, const float* __restrict__ betap,
    const int* __restrict__ ends, int* __restrict__ out) {
#pragma clang fp contract(off)
  __shared__ unsigned char cell[NSITES];  // 64 KiB
  __shared__ uint2 lrec[2][WIN];          // 64 KiB, {uv, r-bits} per slot
  __shared__ int lend[NW * RMAX];         // 4 KiB
  __shared__ float tab[96];
  const int tid = threadIdx.x;
  const float beta = betap[0];

  for (int g = tid; g < NSITES / 4; g += 1024) {
    int4 x = ((const int4*)Xi)[g];
    uchar4 p;
    p.x = (unsigned char)x.x; p.y = (unsigned char)x.y;
    p.z = (unsigned char)x.z; p.w = (unsigned char)x.w;
    ((uchar4*)cell)[g] = p;
  }
  lend[tid] = ends[tid];  // NW*RMAX == 1024
  if (tid < 81) {
    const int mxv = tid / 9, n = tid - mxv * 9;
    const float xn = beta * (float)n;   // fl(beta*n), no FMA (contract off)
    const float xm = beta * (float)mxv; // fl(beta*mx)
    tab[tid] = (float)exp((double)(xn - xm));
  }
  // stage window 0 records (sweep 0)
#pragma unroll
  for (int k = 0; k < 4; ++k) {
    const int i = tid + k * 1024;
    lrec[0][i] = make_uint2((unsigned)recuv[i], __float_as_uint(recr[i]));
  }
  __syncthreads();

  for (int w = 0; w < 2 * NW; ++w) {
    const int ww = w & (NW - 1);
    const int buf = w & 1;
    const uint2* lr = lrec[buf];
    const int* le = &lend[ww * RMAX];
    const bool havenext = (w + 1 < 2 * NW);

    // register-prefetch next window's records (coalesced; off critical path)
    unsigned nuv[4];
    unsigned nr[4];
    if (havenext) {
      const int nww = (w + 1) & (NW - 1), nsw = (w + 1) >> 4;
      const unsigned short* gu = recuv + nww * WIN;
      const float* gr = recr + nsw * NSITES + nww * WIN;
#pragma unroll
      for (int k = 0; k < 4; ++k) {
        nuv[k] = gu[tid + k * 1024];
        nr[k] = __float_as_uint(gr[tid + k * 1024]);
      }
    }

    int nb = 0, ne = le[1];
    uint2 cur = lr[tid];  // round-1 first-iteration record

    for (int rd = 1; rd < RMAX; ++rd) {
      const int b = nb, e = ne;
      if (b >= WIN) break;  // uniform: window complete
      nb = e;
      ne = (rd + 1 < RMAX) ? le[rd + 1] : e;
      // prefetch next round's first-iter record (records are read-only)
      uint2 nxt = make_uint2(0u, 0u);
      if (nb + tid < ne) nxt = lr[nb + tid];
      // execute current round (LDS-only path)
      if (b + tid < e) do_update(cell, tab, (int)cur.x, __uint_as_float(cur.y));
      for (int i = b + tid + 1024; i < e; i += 1024) {
        const uint2 rc = lr[i];
        do_update(cell, tab, (int)rc.x, __uint_as_float(rc.y));
      }
      if (rd == 1 && havenext) {  // stage next window into the other buffer
#pragma unroll
        for (int k = 0; k < 4; ++k)
          lrec[buf ^ 1][tid + k * 1024] = make_uint2(nuv[k], nr[k]);
      }
      __syncthreads();  // round rd writes before round rd+1 reads
      cur = nxt;
    }
  }

  for (int g = tid; g < NSITES / 4; g += 1024) {
    uchar4 p = ((uchar4*)cell)[g];
    int4 o;
    o.x = p.x; o.y = p.y; o.z = p.z; o.w = p.w;
    ((int4*)out)[g] = o;
  }
}

extern "C" void kernel_launch(void* const* d_in, const int* in_sizes, int n_in,
                              void* d_out, int out_size, void* d_ws,
                              size_t ws_size, hipStream_t stream) {
  const int* Xi = (const int*)d_in[0];
  const int* perm = (const int*)d_in[1];
  const float* uni = (const float*)d_in[2];
  const float* beta = (const float*)d_in[3];
  int* out = (int*)d_out;

  char* ws = (char*)d_ws;
  unsigned short* recuv = (unsigned short*)ws;      // 128 KiB
  float* recr = (float*)(ws + 131072);              // 512 KiB
  int* ends = (int*)(ws + 655360);                  // 4 KiB

  GibbsSched_kernel<<<dim3(NW), dim3(1024), 0, stream>>>(perm, uni, recuv,
                                                         recr, ends);
  GibbsSampler_90443421319469_kernel<<<dim3(1), dim3(1024), 0, stream>>>(
      Xi, recuv, recr, beta, ends, out);
}

// Round 6
// 229.391 us; speedup vs baseline: 11.2961x; 1.1688x over previous
//
#include <hip/hip_runtime.h>
#include <math.h>

#define NSITES 65536
#define WIN 4096
#define NW 16          // windows per sweep
#define RMAX 64        // tracked rounds per window (observed depth ~7)

// ws layout:
//   recpk  uint2[2*NSITES]   1048576 B  ({site, uniform-bits} per sorted slot, per sweep)
//   ends   int  [NW*RMAX]       4096 B  (cumulative round boundaries, per window)

// wave-aggregated atomic rank: position for value v in counter array c
// (1-based values, v <= vmax; vmax wave-uniform).
__device__ __forceinline__ int agg_pos(int v, int* c, int vmax) {
  int pos = 0;
  const int lane = threadIdx.x & 63;
  for (int vv = 1; vv <= vmax; ++vv) {
    unsigned long long m = __ballot(v == vv);
    if (m) {
      int leader = __ffsll((long long)m) - 1;
      int base = 0;
      if (lane == leader) base = atomicAdd(&c[vv], (int)__popcll(m));
      base = __shfl(base, leader);
      if (v == vv) pos = base + (int)__popcll(m & ((1ull << lane) - 1ull));
    }
  }
  return pos;
}

// ---------------------------------------------------------------------------
// Kernel A: per-window DAG leveling + counting sort + packed record gather.
// One 1024-thread block per window; window-local position grid in LDS.
// ---------------------------------------------------------------------------
__global__ __launch_bounds__(1024) void GibbsSched_kernel(
    const int* __restrict__ perm, const float* __restrict__ uni,
    uint2* __restrict__ recpk, int* __restrict__ ends) {
  __shared__ unsigned short posg[NSITES];  // 128 KiB: local pos+1, 0 = absent
  __shared__ unsigned short lvl[WIN];      // 8 KiB
  __shared__ int cnt[RMAX + 1], coff[RMAX + 1];
  __shared__ int chg, bmax;
  const int tid = threadIdx.x;
  const int w = blockIdx.x;
  const int wbase = w * WIN;

  for (int g = tid; g < NSITES / 8; g += 1024)  // 8 ushorts per uint4
    ((uint4*)posg)[g] = make_uint4(0u, 0u, 0u, 0u);
  for (int i = tid; i <= RMAX; i += 1024) { cnt[i] = 0; coff[i] = 0; }
  if (tid == 0) bmax = 0;
  __syncthreads();

  int uvk[4];
#pragma unroll
  for (int k = 0; k < 4; ++k) {
    const int lt = tid + k * 1024;
    uvk[k] = perm[wbase + lt];
    posg[uvk[k]] = (unsigned short)(lt + 1);  // sites unique within a sweep
  }
  __syncthreads();

  unsigned short pred[4][8];
  int myl[4];
#pragma unroll
  for (int k = 0; k < 4; ++k) {
    const int lt = tid + k * 1024;
    const int uv = uvk[k], u = uv >> 8, v = uv & 255;
    const int um = u ? u - 1 : 0, up = u < 255 ? u + 1 : 255;
    const int vm = v ? v - 1 : 0, vp = v < 255 ? v + 1 : 255;
    const int nb8[8] = {(um << 8) | vm, (um << 8) | v, (um << 8) | vp,
                        (u << 8) | vm,                 (u << 8) | vp,
                        (up << 8) | vm, (up << 8) | v, (up << 8) | vp};
#pragma unroll
    for (int j = 0; j < 8; ++j) {
      const int p = posg[nb8[j]];  // clipped dup == self -> p-1==lt, excluded
      pred[k][j] = (p && p - 1 < lt) ? (unsigned short)(p - 1)
                                     : (unsigned short)0xFFFF;
    }
    lvl[lt] = 1;
    myl[k] = 1;
  }
  __syncthreads();

  // monotone Jacobi relaxation to the unique longest-path fixpoint
  for (int pass = 0; pass < 128; ++pass) {
    if (tid == 0) chg = 0;
    __syncthreads();
    bool ch = false;
#pragma unroll
    for (int k = 0; k < 4; ++k) {
      int m = 0;
#pragma unroll
      for (int j = 0; j < 8; ++j) {
        const unsigned short p = pred[k][j];
        if (p != 0xFFFF) m = max(m, (int)lvl[p]);
      }
      const int nl = m + 1;  // levels only grow
      if (nl != myl[k]) {
        myl[k] = nl;
        lvl[tid + k * 1024] = (unsigned short)nl;
        ch = true;
      }
    }
    if (ch) chg = 1;
    __syncthreads();
    if (chg == 0) break;  // full no-change pass == converged
  }

#pragma unroll
  for (int k = 0; k < 4; ++k) atomicMax(&bmax, myl[k]);
  __syncthreads();
  const int vmax = bmax;

#pragma unroll
  for (int k = 0; k < 4; ++k) (void)agg_pos(myl[k], cnt, vmax);  // histogram
  __syncthreads();
  if (tid == 0) {
    int e = 0;
    for (int r = 0; r < RMAX; ++r) {  // cnt[0]==0
      coff[r] = e;
      e += cnt[r];
      ends[w * RMAX + r] = e;  // cumulative end through round r
    }
  }
  __syncthreads();

#pragma unroll
  for (int k = 0; k < 4; ++k) {
    const int pos = agg_pos(myl[k], coff, vmax);
    const int lt = tid + k * 1024;
    const int gp = wbase + pos;
    recpk[gp] = make_uint2((unsigned)uvk[k],
                           __float_as_uint(uni[wbase + lt]));          // sweep 0
    recpk[NSITES + gp] = make_uint2((unsigned)uvk[k],
                                    __float_as_uint(uni[NSITES + wbase + lt]));
  }
}

// ---------------------------------------------------------------------------
// Kernel B: executor — 1 block x 1024 threads.
// Per update: 3 row-window LDS reads (2 dwords each) -> neighbor histogram ->
// one float4 ctab read -> 4 compares -> byte write. No divides, no exp.
// ---------------------------------------------------------------------------
__device__ __forceinline__ void do_update(unsigned char* cell,
                                          const unsigned int* cellw,
                                          const float4* ctab, unsigned uvv,
                                          float r) {
  const int u = uvv >> 8, v = (int)(uvv & 255u);
  const int um = u ? u - 1 : 0, up = u < 255 ? u + 1 : 255;
  const int vm = v ? v - 1 : 0, vp = v < 255 ? v + 1 : 255;
  const int cb = vm >> 2;              // dword col of 8-byte window start
  const int sh0 = (vm & 3) << 3;
  const int shv = (v - vm) << 3;       // 0 or 8
  const int shp = (vp - vm) << 3;      // 8 or 16 (or 8 at right border)
  int acc = 0;  // per-class counts in nibbles (class 4 -> bit16, unused)
  {  // top row: cols vm, v, vp (clipped dups included, matching reference)
    const unsigned int* rw = cellw + (um << 6) + cb;
    const unsigned long long wd =
        ((unsigned long long)rw[1] << 32) | (unsigned long long)rw[0];
    const unsigned wl = (unsigned)(wd >> sh0);
    acc += 1 << ((wl & 255u) << 2);
    acc += 1 << (((wl >> shv) & 255u) << 2);
    acc += 1 << (((wl >> shp) & 255u) << 2);
  }
  {  // middle row: cols vm, vp only (true center excluded exactly once)
    const unsigned int* rw = cellw + (u << 6) + cb;
    const unsigned long long wd =
        ((unsigned long long)rw[1] << 32) | (unsigned long long)rw[0];
    const unsigned wl = (unsigned)(wd >> sh0);
    acc += 1 << ((wl & 255u) << 2);
    acc += 1 << (((wl >> shp) & 255u) << 2);
  }
  {  // bottom row: cols vm, v, vp
    const unsigned int* rw = cellw + (up << 6) + cb;
    const unsigned long long wd =
        ((unsigned long long)rw[1] << 32) | (unsigned long long)rw[0];
    const unsigned wl = (unsigned)(wd >> sh0);
    acc += 1 << ((wl & 255u) << 2);
    acc += 1 << (((wl >> shv) & 255u) << 2);
    acc += 1 << (((wl >> shp) & 255u) << 2);
  }
  const int n0 = acc & 15, n1 = (acc >> 4) & 15, n2 = (acc >> 8) & 15;
  const float4 c = ctab[n0 + 9 * n1 + 81 * n2];
  int cnt = (c.x < r) ? 1 : 0;
  cnt += (c.y < r) ? 1 : 0;
  cnt += (c.z < r) ? 1 : 0;
  cnt += (c.w < r) ? 1 : 0;
  cell[uvv] = (unsigned char)cnt;  // 0..4
}

__global__ __launch_bounds__(1024) void GibbsSampler_90443421319469_kernel(
    const int* __restrict__ Xi, const uint2* __restrict__ recpk,
    const float* __restrict__ betap, const int* __restrict__ ends,
    int* __restrict__ out) {
#pragma clang fp contract(off)
  __shared__ __align__(16) unsigned int cellw[NSITES / 4];  // 64 KiB lattice
  __shared__ float4 ctab[732];                              // 11.7 KiB
  __shared__ int lend[NW * RMAX];                           // 4 KiB
  unsigned char* cell = (unsigned char*)cellw;
  const int tid = threadIdx.x;
  const float beta = betap[0];

  for (int g = tid; g < NSITES / 4; g += 1024) {
    int4 x = ((const int4*)Xi)[g];
    // pack 4 int32 cells into one dword (byte lanes)
    cellw[g] = (unsigned)(x.x & 255) | ((unsigned)(x.y & 255) << 8) |
               ((unsigned)(x.z & 255) << 16) | ((unsigned)(x.w & 255) << 24);
  }
  lend[tid] = ends[tid];  // NW*RMAX == 1024
  // cumulative softmax table: bit-identical to per-update reference math
  for (int t = tid; t < 729; t += 1024) {
    const int n0 = t % 9, n1 = (t / 9) % 9, n2 = t / 81;
    const int n3 = 8 - n0 - n1 - n2;
    float4 val = make_float4(2.f, 2.f, 2.f, 2.f);  // unreachable combos
    if (n3 >= 0) {
      const int mx = max(max(n0, n1), max(n2, n3));
      const float xm = beta * (float)mx;   // fl(beta*mx), no FMA (contract off)
      const float x0 = beta * (float)n0;
      const float x1 = beta * (float)n1;
      const float x2 = beta * (float)n2;
      const float x3 = beta * (float)n3;
      const float e0 = (float)exp((double)(x0 - xm));
      const float e1 = (float)exp((double)(x1 - xm));
      const float e2 = (float)exp((double)(x2 - xm));
      const float e3 = (float)exp((double)(x3 - xm));
      const float s = ((e0 + e1) + e2) + e3;  // sequential sum, like np/XLA
      const float c0 = e0 / s;                // IEEE f32 divides, like ref
      const float c1 = c0 + e1 / s;
      const float c2 = c1 + e2 / s;
      const float c3 = c2 + e3 / s;
      val = make_float4(c0, c1, c2, c3);
    }
    ctab[t] = val;
  }
  __syncthreads();

  for (int w = 0; w < 2 * NW; ++w) {
    const int ww = w & (NW - 1);
    const int sw = w >> 4;  // sweep index (NW==16)
    const uint2* rp = recpk + sw * NSITES + ww * WIN;
    const int* le = &lend[ww * RMAX];

    int nb = 0, ne = le[1];
    uint2 cur = make_uint2(0u, 0u);
    if (tid < ne) cur = rp[tid];  // round-1 first-iteration record

    for (int rd = 1; rd < RMAX; ++rd) {
      const int b = nb, e = ne;
      if (b >= WIN) break;  // uniform: window complete
      nb = e;
      ne = (rd + 1 < RMAX) ? le[rd + 1] : e;
      // prefetch next round's first-iter record (read-only stream)
      uint2 nxt = make_uint2(0u, 0u);
      if (nb + tid < ne) nxt = rp[nb + tid];
      // execute current round
      if (b + tid < e) do_update(cell, cellw, ctab, cur.x, __uint_as_float(cur.y));
      for (int i = b + tid + 1024; i < e; i += 1024) {
        const uint2 rc = rp[i];
        do_update(cell, cellw, ctab, rc.x, __uint_as_float(rc.y));
      }
      __syncthreads();  // round rd writes before round rd+1 reads
      cur = nxt;
    }
  }

  for (int g = tid; g < NSITES / 4; g += 1024) {
    const unsigned p = cellw[g];
    int4 o;
    o.x = (int)(p & 255u);
    o.y = (int)((p >> 8) & 255u);
    o.z = (int)((p >> 16) & 255u);
    o.w = (int)((p >> 24) & 255u);
    ((int4*)out)[g] = o;
  }
}

extern "C" void kernel_launch(void* const* d_in, const int* in_sizes, int n_in,
                              void* d_out, int out_size, void* d_ws,
                              size_t ws_size, hipStream_t stream) {
  const int* Xi = (const int*)d_in[0];
  const int* perm = (const int*)d_in[1];
  const float* uni = (const float*)d_in[2];
  const float* beta = (const float*)d_in[3];
  int* out = (int*)d_out;

  char* ws = (char*)d_ws;
  uint2* recpk = (uint2*)ws;                 // 1 MiB
  int* ends = (int*)(ws + 2 * NSITES * 8);   // 4 KiB

  GibbsSched_kernel<<<dim3(NW), dim3(1024), 0, stream>>>(perm, uni, recpk,
                                                         ends);
  GibbsSampler_90443421319469_kernel<<<dim3(1), dim3(1024), 0, stream>>>(
      Xi, recpk, beta, ends, out);
}